// Round 3
// baseline (660.142 us; speedup 1.0000x reference)
//
#include <hip/hip_runtime.h>
#include <hip/hip_bf16.h>

__device__ __forceinline__ float silu_f(float x) { return x / (1.f + __expf(-x)); }

// tact[b,d] = silu(t[b]*te_w1[d] + te_b1[d]),  [512,512]
__global__ __launch_bounds__(256) void tact_kernel(const float* __restrict__ t,
                                                   const float* __restrict__ w1,
                                                   const float* __restrict__ b1,
                                                   float* __restrict__ out) {
  int i = blockIdx.x * 256 + threadIdx.x;  // 512*512 = 262144
  int b = i >> 9, d = i & 511;
  float pre = t[b] * w1[d] + b1[d];
  out[i] = silu_f(pre);
}

// ---------------- generic f32 GEMM ----------------
// C = ACT(alpha*(A@B) + bias); 32x32 tile, 256 threads, 2x2/thread.
// ACT: 0=none, 1=silu, 2=tanh. Requires M,N,K multiples of 32.
template <int ACT>
__global__ __launch_bounds__(256) void gemm_kernel(
    const float* __restrict__ A, int lda, const float* __restrict__ Bw, int ldb,
    const float* __restrict__ bias, float* __restrict__ C,
    int ldc, int K, float alpha) {
  __shared__ float As[32][33];  // [k][m] (transposed)
  __shared__ float Bs[32][33];  // [k][n]
  const int tid = threadIdx.x;
  const int tx = tid & 15;   // n
  const int ty = tid >> 4;   // m
  const int bm = blockIdx.y * 32;
  const int bn = blockIdx.x * 32;
  const int lr = tid >> 5;   // 0..7
  const int lc = tid & 31;   // 0..31
  float c00 = 0.f, c01 = 0.f, c10 = 0.f, c11 = 0.f;
  const float* Ab = A + (long)bm * lda;
  const float* Bb = Bw + bn;
  for (int k0 = 0; k0 < K; k0 += 32) {
#pragma unroll
    for (int e = 0; e < 4; ++e) {
      int m = lr + e * 8;
      As[lc][m] = Ab[(long)m * lda + (k0 + lc)];
      int kr = lr + e * 8;
      Bs[kr][lc] = Bb[(long)(k0 + kr) * ldb + lc];
    }
    __syncthreads();
#pragma unroll
    for (int k = 0; k < 32; ++k) {
      float a0 = As[k][2 * ty], a1 = As[k][2 * ty + 1];
      float b0 = Bs[k][2 * tx], b1 = Bs[k][2 * tx + 1];
      c00 += a0 * b0; c01 += a0 * b1;
      c10 += a1 * b0; c11 += a1 * b1;
    }
    __syncthreads();
  }
  int r0 = bm + 2 * ty, n0 = bn + 2 * tx;
  float bb0 = bias ? bias[n0] : 0.f;
  float bb1 = bias ? bias[n0 + 1] : 0.f;
  float o00 = alpha * c00 + bb0, o01 = alpha * c01 + bb1;
  float o10 = alpha * c10 + bb0, o11 = alpha * c11 + bb1;
  if (ACT == 1) { o00 = silu_f(o00); o01 = silu_f(o01); o10 = silu_f(o10); o11 = silu_f(o11); }
  if (ACT == 2) { o00 = tanhf(o00); o01 = tanhf(o01); o10 = tanhf(o10); o11 = tanhf(o11); }
  C[(long)r0 * ldc + n0] = o00;
  C[(long)r0 * ldc + n0 + 1] = o01;
  C[(long)(r0 + 1) * ldc + n0] = o10;
  C[(long)(r0 + 1) * ldc + n0 + 1] = o11;
}

// out[r, h*128+j] = sum_d A[r, h*64+d] * kfp[j, h*64+d]
// grid (H=8, R), block 128 (thread = j)
__global__ __launch_bounds__(128) void qk_kernel(const float* __restrict__ Arows,
                                                 const float* __restrict__ kfp,
                                                 float* __restrict__ out) {
  int h = blockIdx.x;
  int r = blockIdx.y;
  int j = threadIdx.x;
  const float* a = Arows + (long)r * 512 + h * 64;
  const float* kk = kfp + (long)j * 512 + h * 64;
  float acc = 0.f;
#pragma unroll
  for (int d = 0; d < 64; ++d) acc += a[d] * kk[d];
  out[(long)r * 1024 + h * 128 + j] = acc;
}

// ---------------- fused sparse attention + pooling ----------------
// logits T[i,j] = U[b,h,j] + M[h,i,j]; per row keep top-64 (>= 64th largest),
// softmax, column-mean over i, then pool[b,h*64+d] = vb + sum_j w[j]*vf[j,d].
__global__ __launch_bounds__(256) void attn_kernel(
    const float* __restrict__ U,   // [512][1024]  (b, h*128+j)
    const float* __restrict__ Mm,  // [128][1024]  (i, h*128+j)
    const float* __restrict__ vb,  // [512][512]
    const float* __restrict__ vf,  // [128][512]
    float* __restrict__ pool)      // [512][512]
{
  const int b = blockIdx.x, h = blockIdx.y;
  const int lane = threadIdx.x & 63;
  const int wave = threadIdx.x >> 6;  // 0..3
  __shared__ float wpart[4][128];
  __shared__ float wcol[128];
  __shared__ float ppart[2][64];

  const float* ub = U + (long)b * 1024 + h * 128;
  const float u0 = ub[lane], u1 = ub[lane + 64];
  float wc0 = 0.f, wc1 = 0.f;
  const float* Mh = Mm + h * 128;
  const int i0 = wave * 32;
  float nm0 = Mh[(long)i0 * 1024 + lane];
  float nm1 = Mh[(long)i0 * 1024 + lane + 64];
  for (int r = 0; r < 32; ++r) {
    float T0 = u0 + nm0, T1 = u1 + nm1;
    if (r < 31) {  // prefetch next M row
      nm0 = Mh[(long)(i0 + r + 1) * 1024 + lane];
      nm1 = Mh[(long)(i0 + r + 1) * 1024 + lane + 64];
    }
    // order-preserving uint transform
    unsigned a0 = __float_as_uint(T0);
    unsigned s0 = a0 ^ ((unsigned)((int)a0 >> 31) | 0x80000000u);
    unsigned a1 = __float_as_uint(T1);
    unsigned s1 = a1 ^ ((unsigned)((int)a1 >> 31) | 0x80000000u);
    // binary search for 64th-largest (top 20 bits; ties at 2^-12 rel are harmless)
    unsigned thr = 0u;
#pragma unroll
    for (int bit = 31; bit >= 12; --bit) {
      unsigned cand = thr | (1u << bit);
      int n = __popcll(__ballot(s0 >= cand)) + __popcll(__ballot(s1 >= cand));
      if (n >= 64) thr = cand;
    }
    float mx = fmaxf(T0, T1);
#pragma unroll
    for (int d = 1; d < 64; d <<= 1) mx = fmaxf(mx, __shfl_xor(mx, d));
    float p0 = (s0 >= thr) ? __expf(T0 - mx) : 0.f;
    float p1 = (s1 >= thr) ? __expf(T1 - mx) : 0.f;
    float sm = p0 + p1;
#pragma unroll
    for (int d = 1; d < 64; d <<= 1) sm += __shfl_xor(sm, d);
    float inv = 1.f / sm;
    wc0 += p0 * inv;
    wc1 += p1 * inv;
  }
  wpart[wave][lane] = wc0;
  wpart[wave][lane + 64] = wc1;
  __syncthreads();
  if (threadIdx.x < 128) {
    wcol[threadIdx.x] = (wpart[0][threadIdx.x] + wpart[1][threadIdx.x] +
                         wpart[2][threadIdx.x] + wpart[3][threadIdx.x]) * (1.f / 128.f);
  }
  __syncthreads();
  if (wave < 2) {
    int j0 = wave * 64;
    const float* vfp = vf + h * 64 + lane;
    float acc = 0.f;
#pragma unroll 8
    for (int jj = 0; jj < 64; ++jj) acc += wcol[j0 + jj] * vfp[(long)(j0 + jj) * 512];
    ppart[wave][lane] = acc;
  }
  __syncthreads();
  if (threadIdx.x < 64) {
    int d = threadIdx.x;
    pool[(long)b * 512 + h * 64 + d] =
        ppart[0][d] + ppart[1][d] + vb[(long)b * 512 + h * 64 + d];
  }
}

// LayerNorm over 512 cols, eps 1e-5, affine
__global__ __launch_bounds__(256) void ln_kernel(const float* __restrict__ X,
                                                 const float* __restrict__ g,
                                                 const float* __restrict__ bb,
                                                 float* __restrict__ Y) {
  int row = blockIdx.x;
  const float* x = X + (long)row * 512;
  int tid = threadIdx.x;
  float v0 = x[tid], v1 = x[tid + 256];
  float s = v0 + v1;
#pragma unroll
  for (int d = 1; d < 64; d <<= 1) s += __shfl_xor(s, d);
  __shared__ float r1[4], r2[4];
  if ((tid & 63) == 0) r1[tid >> 6] = s;
  __syncthreads();
  float mean = (r1[0] + r1[1] + r1[2] + r1[3]) * (1.f / 512.f);
  float d0 = v0 - mean, d1 = v1 - mean;
  float q = d0 * d0 + d1 * d1;
#pragma unroll
  for (int d = 1; d < 64; d <<= 1) q += __shfl_xor(q, d);
  if ((tid & 63) == 0) r2[tid >> 6] = q;
  __syncthreads();
  float var = (r2[0] + r2[1] + r2[2] + r2[3]) * (1.f / 512.f);
  float inv = rsqrtf(var + 1e-5f);
  Y[(long)row * 512 + tid] = d0 * inv * g[tid] + bb[tid];
  Y[(long)row * 512 + tid + 256] = d1 * inv * g[tid + 256] + bb[tid + 256];
}

// ---------------- host ----------------

extern "C" void kernel_launch(void* const* d_in, const int* in_sizes, int n_in,
                              void* d_out, int out_size, void* d_ws, size_t ws_size,
                              hipStream_t stream) {
  const float* x_t = (const float*)d_in[0];
  const float* t_in = (const float*)d_in[1];
  const float* te_w1 = (const float*)d_in[2];
  const float* te_b1 = (const float*)d_in[3];
  const float* te_w2 = (const float*)d_in[4];
  const float* te_b2 = (const float*)d_in[5];
  const float* fe_w1 = (const float*)d_in[6];
  const float* fe_b1 = (const float*)d_in[7];
  const float* fe_w2 = (const float*)d_in[8];
  const float* fe_b2 = (const float*)d_in[9];
  const float* fp_w1 = (const float*)d_in[10];
  const float* fp_b1 = (const float*)d_in[11];
  const float* fp_w2 = (const float*)d_in[12];
  const float* fp_b2 = (const float*)d_in[13];
  const float* fp_w3 = (const float*)d_in[14];
  const float* fp_b3 = (const float*)d_in[15];
  const float* fid = (const float*)d_in[16];
  const float* wq = (const float*)d_in[17];
  const float* bq = (const float*)d_in[18];
  const float* wk = (const float*)d_in[19];
  // d_in[20]=bk cancels in softmax (row-constant along j) -> unused
  const float* wv = (const float*)d_in[21];
  const float* bv = (const float*)d_in[22];
  const float* wo = (const float*)d_in[23];
  const float* bo = (const float*)d_in[24];
  const float* gp_w1 = (const float*)d_in[25];
  const float* gp_b1 = (const float*)d_in[26];
  const float* gp_w2 = (const float*)d_in[27];
  const float* gp_b2 = (const float*)d_in[28];
  const float* ln_g = (const float*)d_in[29];
  const float* ln_b = (const float*)d_in[30];
  const float* dn_w1 = (const float*)d_in[31];
  const float* dn_b1 = (const float*)d_in[32];
  const float* dn_w2 = (const float*)d_in[33];
  const float* dn_b2 = (const float*)d_in[34];
  const float* dn_w3 = (const float*)d_in[35];
  const float* dn_b3 = (const float*)d_in[36];

  float* W = (float*)d_ws;
  // Tight aliasing schedule (7.25 MiB total), liveness-verified:
  float* S0 = W;                  // 524288: xcat -> qb(lo)/vb(hi) -> r2
  float* S1 = W + 524288;         // 524288: u -> g2 -> r1
  float* S2 = W + 1048576;        // 262144: tact -> h1 -> base -> g1 -> gn
  float* S3 = W + 1310720;        // 262144: act1 -> h2 -> pool -> g3
  float* T0 = W + 1572864;        // 65536: qf
  float* T1 = W + 1638400;        // 65536: kfp
  float* T2 = W + 1703936;        // 65536: vf
  float* T3 = W + 1769472;        // 131072: M
  float* qb = S0;                 // [512,512]
  float* vbuf = S0 + 262144;      // [512,512]
  // total 1900544 floats = 7.25 MiB

  auto gemm = [&](int act, const float* A, int lda, const float* Bw, int ldb,
                  const float* bias, float* C, int ldc, int M, int N, int K,
                  float alpha) {
    dim3 g(N / 32, M / 32);
    if (act == 1)
      gemm_kernel<1><<<g, 256, 0, stream>>>(A, lda, Bw, ldb, bias, C, ldc, K, alpha);
    else if (act == 2)
      gemm_kernel<2><<<g, 256, 0, stream>>>(A, lda, Bw, ldb, bias, C, ldc, K, alpha);
    else
      gemm_kernel<0><<<g, 256, 0, stream>>>(A, lda, Bw, ldb, bias, C, ldc, K, alpha);
  };

  // time embedding activation
  tact_kernel<<<262144 / 256, 256, 0, stream>>>(t_in, te_w1, te_b1, S2);

  // embeddings -> xcat = [x_emb | t_emb]  (S0, [512,1024])
  gemm(1, x_t, 128, fe_w1, 512, fe_b1, S3, 512, 512, 512, 128, 1.f);       // act1
  gemm(0, S3, 512, fe_w2, 512, fe_b2, S0, 1024, 512, 512, 512, 1.f);       // x_emb
  gemm(0, S2, 512, te_w2, 512, te_b2, S0 + 512, 1024, 512, 512, 512, 1.f); // t_emb

  // per-b feature processor (broadcast-collapsed: comb is f-independent)
  gemm(1, S0, 1024, fp_w1, 512, fp_b1, S2, 512, 512, 512, 1024, 1.f);  // h1 (S0 dead after)
  gemm(1, S2, 512, fp_w2, 512, fp_b2, S3, 512, 512, 512, 512, 1.f);   // h2
  gemm(0, S3, 512, fp_w3, 512, fp_b3, S2, 512, 512, 512, 512, 1.f);   // base

  // q/v base parts and fid parts (kf' absorbs 0.1 and 1/8 scale)
  gemm(0, S2, 512, wq, 512, bq, qb, 512, 512, 512, 512, 1.f);          // qb
  gemm(0, S2, 512, wv, 512, bv, vbuf, 512, 512, 512, 512, 1.f);        // vb
  gemm(0, fid, 128, wq, 512, nullptr, T0, 512, 128, 512, 128, 0.1f);   // qf
  gemm(0, fid, 128, wk, 512, nullptr, T1, 512, 128, 512, 128, 0.0125f);// kf' = 0.1/8 * fid@wk[:128]
  gemm(0, fid, 128, wv, 512, nullptr, T2, 512, 128, 512, 128, 0.1f);   // vf

  // M[h,i,j] (b-independent) and u[b,h,j]
  qk_kernel<<<dim3(8, 128), 128, 0, stream>>>(T0, T1, T3);  // M
  qk_kernel<<<dim3(8, 512), 128, 0, stream>>>(qb, T1, S1);  // u

  // fused sparse attention + mean-pool  -> pool (S3)
  attn_kernel<<<dim3(512, 8), 256, 0, stream>>>(S1, T3, vbuf, T2, S3);

  // global processor
  gemm(0, S3, 512, wo, 512, bo, S2, 512, 512, 512, 512, 1.f);            // g1
  gemm(1, S2, 512, gp_w1, 1024, gp_b1, S1, 1024, 512, 1024, 512, 1.f);   // g2 (u dead)
  gemm(0, S1, 1024, gp_w2, 512, gp_b2, S3, 512, 512, 512, 1024, 1.f);    // g3
  ln_kernel<<<512, 256, 0, stream>>>(S3, ln_g, ln_b, S2);                // gn

  // denoise net -> tanh of first 128 cols (f32 output)
  gemm(1, S2, 512, dn_w1, 1024, dn_b1, S1, 1024, 512, 1024, 512, 1.f);   // r1
  gemm(1, S1, 1024, dn_w2, 1024, dn_b2, S0, 1024, 512, 1024, 1024, 1.f); // r2 (qb/vb dead)
  gemm(2, S0, 1024, dn_w3, 256, dn_b3, (float*)d_out, 128, 512, 128, 1024, 1.f);
}

// Round 4
// 370.793 us; speedup vs baseline: 1.7804x; 1.7804x over previous
//
#include <hip/hip_runtime.h>
#include <hip/hip_bf16.h>

__device__ __forceinline__ float silu_f(float x) { return x / (1.f + __expf(-x)); }

// tact[b,d] = silu(t[b]*te_w1[d] + te_b1[d]),  [512,512]
__global__ __launch_bounds__(256) void tact_kernel(const float* __restrict__ t,
                                                   const float* __restrict__ w1,
                                                   const float* __restrict__ b1,
                                                   float* __restrict__ out) {
  int i = blockIdx.x * 256 + threadIdx.x;  // 262144
  int b = i >> 9, d = i & 511;
  out[i] = silu_f(t[b] * w1[d] + b1[d]);
}

// ---------------- 64x64-tile f32 GEMM, 4x4/thread, optional split-K / z-batch ----------------
// PART=1: grid.z = K-slab index; writes raw partials to OUT[z*slabMN + r*ldc + c] (ldc==N).
// PART=0: grid.z batches independent problems via zAoff/zBoff/zCoff; epilogue = ACT(alpha*acc+bias).
// BT=1: B stored [N][K] (transposed-staging). M,N mult of 64; K (per slab) mult of 32.
template <int ACT, int BT, int PART>
__global__ __launch_bounds__(256) void gemm64(
    const float* __restrict__ A, int lda,
    const float* __restrict__ B, int ldb,
    const float* __restrict__ bias,
    float* __restrict__ OUT, int ldc,
    int K, float alpha, int zAoff, int zBoff, int zCoff, int slabMN) {
  __shared__ float As[32][68];  // [k][m], pad 68: float4-aligned rows, spread banks
  __shared__ float Bs[32][68];  // [k][n]
  const int tid = threadIdx.x;
  const int z = blockIdx.z;
  const long bm = blockIdx.y * 64, bn = blockIdx.x * 64;
  const float* Ap = PART ? A + (long)z * K : A + (long)z * zAoff;
  const float* Bp = PART ? (BT ? B + (long)z * K : B + (long)z * K * ldb)
                         : B + (long)z * zBoff;
  float acc[4][4] = {};
  const int ar = tid >> 3;        // 0..31
  const int ak = (tid & 7) << 2;  // 0..28
  const int br = tid >> 4;        // 0..15
  const int bn4 = (tid & 15) << 2;
  const int ty = tid >> 4, tx = tid & 15;
  for (int k0 = 0; k0 < K; k0 += 32) {
#pragma unroll
    for (int h = 0; h < 2; ++h) {  // A tile 64m x 32k -> As[k][m]
      int m = ar + h * 32;
      float4 av = *(const float4*)&Ap[(bm + m) * (long)lda + k0 + ak];
      As[ak + 0][m] = av.x; As[ak + 1][m] = av.y;
      As[ak + 2][m] = av.z; As[ak + 3][m] = av.w;
    }
    if (BT) {
#pragma unroll
      for (int h = 0; h < 2; ++h) {  // B [N][K] tile 64n x 32k -> Bs[k][n]
        int n = ar + h * 32;
        float4 bv = *(const float4*)&Bp[(bn + n) * (long)ldb + k0 + ak];
        Bs[ak + 0][n] = bv.x; Bs[ak + 1][n] = bv.y;
        Bs[ak + 2][n] = bv.z; Bs[ak + 3][n] = bv.w;
      }
    } else {
#pragma unroll
      for (int h = 0; h < 2; ++h) {  // B [K][N] tile 32k x 64n
        int kk = br + h * 16;
        *(float4*)&Bs[kk][bn4] = *(const float4*)&Bp[(k0 + kk) * (long)ldb + bn + bn4];
      }
    }
    __syncthreads();
#pragma unroll
    for (int k = 0; k < 32; ++k) {
      float4 a4 = *(const float4*)&As[k][ty << 2];
      float4 b4 = *(const float4*)&Bs[k][tx << 2];
      float am[4] = {a4.x, a4.y, a4.z, a4.w};
      float bv[4] = {b4.x, b4.y, b4.z, b4.w};
#pragma unroll
      for (int i = 0; i < 4; ++i)
#pragma unroll
        for (int j = 0; j < 4; ++j) acc[i][j] = fmaf(am[i], bv[j], acc[i][j]);
    }
    __syncthreads();
  }
  if (PART) {
    float* O = OUT + (long)z * slabMN + (bm + ty * 4) * (long)ldc + bn + tx * 4;
#pragma unroll
    for (int i = 0; i < 4; ++i) {
      float4 v = {acc[i][0], acc[i][1], acc[i][2], acc[i][3]};
      *(float4*)&O[(long)i * ldc] = v;
    }
  } else {
    long c0 = bn + tx * 4;
    float b0 = bias ? bias[c0] : 0.f, b1 = bias ? bias[c0 + 1] : 0.f;
    float b2 = bias ? bias[c0 + 2] : 0.f, b3 = bias ? bias[c0 + 3] : 0.f;
    float* O = OUT + (long)z * zCoff + (bm + ty * 4) * (long)ldc + c0;
#pragma unroll
    for (int i = 0; i < 4; ++i) {
      float v0 = alpha * acc[i][0] + b0, v1 = alpha * acc[i][1] + b1;
      float v2 = alpha * acc[i][2] + b2, v3 = alpha * acc[i][3] + b3;
      if (ACT == 1) { v0 = silu_f(v0); v1 = silu_f(v1); v2 = silu_f(v2); v3 = silu_f(v3); }
      if (ACT == 2) { v0 = tanhf(v0); v1 = tanhf(v1); v2 = tanhf(v2); v3 = tanhf(v3); }
      float4 v = {v0, v1, v2, v3};
      *(float4*)&O[(long)i * ldc] = v;
    }
  }
}

// reduce split-K partials: C = ACT(alpha*sum_s P[s] + bias)
template <int ACT>
__global__ __launch_bounds__(256) void reduceK(
    const float* __restrict__ P, int slabMN, int nslab,
    const float* __restrict__ bias, float* __restrict__ C,
    int Nmask, int logN, int ldc, float alpha) {
  int i4 = (blockIdx.x * 256 + threadIdx.x) << 2;
  float4 s = *(const float4*)&P[i4];
  for (int si = 1; si < nslab; ++si) {
    float4 p = *(const float4*)&P[(long)si * slabMN + i4];
    s.x += p.x; s.y += p.y; s.z += p.z; s.w += p.w;
  }
  int r = i4 >> logN;
  int c = i4 & Nmask;
  float b0 = 0.f, b1 = 0.f, b2 = 0.f, b3 = 0.f;
  if (bias) { b0 = bias[c]; b1 = bias[c + 1]; b2 = bias[c + 2]; b3 = bias[c + 3]; }
  float v0 = alpha * s.x + b0, v1 = alpha * s.y + b1;
  float v2 = alpha * s.z + b2, v3 = alpha * s.w + b3;
  if (ACT == 1) { v0 = silu_f(v0); v1 = silu_f(v1); v2 = silu_f(v2); v3 = silu_f(v3); }
  if (ACT == 2) { v0 = tanhf(v0); v1 = tanhf(v1); v2 = tanhf(v2); v3 = tanhf(v3); }
  float4 v = {v0, v1, v2, v3};
  *(float4*)&C[(long)r * ldc + c] = v;
}

// ---------------- fused sparse attention + pooling ----------------
// logits T[i,j] = U[b,h,j] + M[h,i,j]; keep top-64 per row (>= 64th largest),
// softmax, column-mean over i, pool[b,h*64+d] = vb + sum_j w[j]*vf[j,d].
__global__ __launch_bounds__(256) void attn_kernel(
    const float* __restrict__ U,   // [512][1024]
    const float* __restrict__ Mm,  // [128][1024]
    const float* __restrict__ vb,  // [512][512]
    const float* __restrict__ vf,  // [128][512]
    float* __restrict__ pool)      // [512][512]
{
  const int b = blockIdx.x, h = blockIdx.y;
  const int lane = threadIdx.x & 63;
  const int wave = threadIdx.x >> 6;
  __shared__ float wpart[4][128];
  __shared__ float wcol[128];
  __shared__ float ppart[2][64];

  const float* ub = U + (long)b * 1024 + h * 128;
  const float u0 = ub[lane], u1 = ub[lane + 64];
  float wc0 = 0.f, wc1 = 0.f;
  const float* Mh = Mm + h * 128;
  const int i0 = wave * 32;
  float nm0 = Mh[(long)i0 * 1024 + lane];
  float nm1 = Mh[(long)i0 * 1024 + lane + 64];
  for (int r = 0; r < 32; ++r) {
    float T0 = u0 + nm0, T1 = u1 + nm1;
    if (r < 31) {
      nm0 = Mh[(long)(i0 + r + 1) * 1024 + lane];
      nm1 = Mh[(long)(i0 + r + 1) * 1024 + lane + 64];
    }
    unsigned a0 = __float_as_uint(T0);
    unsigned s0 = a0 ^ ((unsigned)((int)a0 >> 31) | 0x80000000u);
    unsigned a1 = __float_as_uint(T1);
    unsigned s1 = a1 ^ ((unsigned)((int)a1 >> 31) | 0x80000000u);
    // 17-step binary search for 64th-largest key (bits 31..15; 2^-8 rel precision —
    // near-tie inclusions perturb near-equal softmax weights only)
    unsigned thr = 0u;
#pragma unroll
    for (int bit = 31; bit >= 15; --bit) {
      unsigned cand = thr | (1u << bit);
      int n = __popcll(__ballot(s0 >= cand)) + __popcll(__ballot(s1 >= cand));
      if (n >= 64) thr = cand;
    }
    // exp shift = threshold value (kept logits satisfy 0 <= T - shift <= spread ~ O(1))
    unsigned au = (thr & 0x80000000u) ? (thr ^ 0x80000000u) : ~thr;
    float shift = __uint_as_float(au);
    float p0 = (s0 >= thr) ? __expf(T0 - shift) : 0.f;
    float p1 = (s1 >= thr) ? __expf(T1 - shift) : 0.f;
    float sm = p0 + p1;
#pragma unroll
    for (int d = 1; d < 64; d <<= 1) sm += __shfl_xor(sm, d);
    float inv = 1.f / sm;
    wc0 += p0 * inv;
    wc1 += p1 * inv;
  }
  wpart[wave][lane] = wc0;
  wpart[wave][lane + 64] = wc1;
  __syncthreads();
  if (threadIdx.x < 128) {
    wcol[threadIdx.x] = (wpart[0][threadIdx.x] + wpart[1][threadIdx.x] +
                         wpart[2][threadIdx.x] + wpart[3][threadIdx.x]) * (1.f / 128.f);
  }
  __syncthreads();
  if (wave < 2) {
    int j0 = wave * 64;
    const float* vfp = vf + h * 64 + lane;
    float acc = 0.f;
#pragma unroll 8
    for (int jj = 0; jj < 64; ++jj) acc += wcol[j0 + jj] * vfp[(long)(j0 + jj) * 512];
    ppart[wave][lane] = acc;
  }
  __syncthreads();
  if (threadIdx.x < 64) {
    int d = threadIdx.x;
    pool[(long)b * 512 + h * 64 + d] =
        ppart[0][d] + ppart[1][d] + vb[(long)b * 512 + h * 64 + d];
  }
}

// LayerNorm over 512 cols, eps 1e-5, affine
__global__ __launch_bounds__(256) void ln_kernel(const float* __restrict__ X,
                                                 const float* __restrict__ g,
                                                 const float* __restrict__ bb,
                                                 float* __restrict__ Y) {
  int row = blockIdx.x;
  const float* x = X + (long)row * 512;
  int tid = threadIdx.x;
  float v0 = x[tid], v1 = x[tid + 256];
  float s = v0 + v1;
#pragma unroll
  for (int d = 1; d < 64; d <<= 1) s += __shfl_xor(s, d);
  __shared__ float r1[4], r2[4];
  if ((tid & 63) == 0) r1[tid >> 6] = s;
  __syncthreads();
  float mean = (r1[0] + r1[1] + r1[2] + r1[3]) * (1.f / 512.f);
  float d0 = v0 - mean, d1 = v1 - mean;
  float q = d0 * d0 + d1 * d1;
#pragma unroll
  for (int d = 1; d < 64; d <<= 1) q += __shfl_xor(q, d);
  if ((tid & 63) == 0) r2[tid >> 6] = q;
  __syncthreads();
  float var = (r2[0] + r2[1] + r2[2] + r2[3]) * (1.f / 512.f);
  float inv = rsqrtf(var + 1e-5f);
  Y[(long)row * 512 + tid] = d0 * inv * g[tid] + bb[tid];
  Y[(long)row * 512 + tid + 256] = d1 * inv * g[tid + 256] + bb[tid + 256];
}

// ---------------- host ----------------

extern "C" void kernel_launch(void* const* d_in, const int* in_sizes, int n_in,
                              void* d_out, int out_size, void* d_ws, size_t ws_size,
                              hipStream_t stream) {
  const float* x_t = (const float*)d_in[0];
  const float* t_in = (const float*)d_in[1];
  const float* te_w1 = (const float*)d_in[2];
  const float* te_b1 = (const float*)d_in[3];
  const float* te_w2 = (const float*)d_in[4];
  const float* te_b2 = (const float*)d_in[5];
  const float* fe_w1 = (const float*)d_in[6];
  const float* fe_b1 = (const float*)d_in[7];
  const float* fe_w2 = (const float*)d_in[8];
  const float* fe_b2 = (const float*)d_in[9];
  const float* fp_w1 = (const float*)d_in[10];
  const float* fp_b1 = (const float*)d_in[11];
  const float* fp_w2 = (const float*)d_in[12];
  const float* fp_b2 = (const float*)d_in[13];
  const float* fp_w3 = (const float*)d_in[14];
  const float* fp_b3 = (const float*)d_in[15];
  const float* fid = (const float*)d_in[16];
  const float* wq = (const float*)d_in[17];
  const float* bq = (const float*)d_in[18];
  const float* wk = (const float*)d_in[19];
  // d_in[20]=bk cancels (row-constant in softmax) -> unused
  const float* wv = (const float*)d_in[21];
  const float* bv = (const float*)d_in[22];
  const float* wo = (const float*)d_in[23];
  const float* bo = (const float*)d_in[24];
  const float* gp_w1 = (const float*)d_in[25];
  const float* gp_b1 = (const float*)d_in[26];
  const float* gp_w2 = (const float*)d_in[27];
  const float* gp_b2 = (const float*)d_in[28];
  const float* ln_g = (const float*)d_in[29];
  const float* ln_b = (const float*)d_in[30];
  const float* dn_w1 = (const float*)d_in[31];
  const float* dn_b1 = (const float*)d_in[32];
  const float* dn_w2 = (const float*)d_in[33];
  const float* dn_b2 = (const float*)d_in[34];
  const float* dn_w3 = (const float*)d_in[35];
  const float* dn_b3 = (const float*)d_in[36];

  float* W = (float*)d_ws;
  float* P  = W;                  // 1,048,576 floats (4 MB): split-K partial slabs
  float* S0 = W + 1048576;        // 524288: xcat -> {qb, vb} -> r2out
  float* S1 = W + 1572864;        // 524288: u -> g2out -> r1out
  float* S2 = W + 2097152;        // 262144: tact -> h1 -> base -> g1out -> gn
  float* S3 = W + 2359296;        // 262144: act1 -> h2 -> pool -> g3out
  float* T0 = W + 2621440;        // 65536: qf
  float* T1 = W + 2686976;        // 65536: kfp
  float* T2 = W + 2752512;        // 65536: vf
  float* T3 = W + 2818048;        // 131072: M
  float* qb = S0;
  float* vbuf = S0 + 262144;
  // total 2,949,120 floats = 11.25 MiB

  // split-K partial gemm (raw partials into P)
  auto gpart = [&](const float* A, int lda, const float* B, int ldb,
                   int M, int N, int K, int split) {
    dim3 g(N / 64, M / 64, split);
    gemm64<0, 0, 1><<<g, 256, 0, stream>>>(A, lda, B, ldb, nullptr, P, N,
                                           K / split, 1.f, 0, 0, 0, M * N);
  };
  auto gred = [&](int act, const float* bias, float* C, int N, int logN, int ldc,
                  int slabMN, int nslab, float alpha) {
    dim3 g(slabMN / 1024);
    if (act == 0)
      reduceK<0><<<g, 256, 0, stream>>>(P, slabMN, nslab, bias, C, N - 1, logN, ldc, alpha);
    else if (act == 1)
      reduceK<1><<<g, 256, 0, stream>>>(P, slabMN, nslab, bias, C, N - 1, logN, ldc, alpha);
    else
      reduceK<2><<<g, 256, 0, stream>>>(P, slabMN, nslab, bias, C, N - 1, logN, ldc, alpha);
  };
  // direct gemm with epilogue
  auto gfull = [&](int act, const float* A, int lda, const float* B, int ldb,
                   const float* bias, float* C, int ldc, int M, int N, int K,
                   float alpha) {
    dim3 g(N / 64, M / 64, 1);
    if (act == 0)
      gemm64<0, 0, 0><<<g, 256, 0, stream>>>(A, lda, B, ldb, bias, C, ldc, K, alpha, 0, 0, 0, 0);
    else if (act == 1)
      gemm64<1, 0, 0><<<g, 256, 0, stream>>>(A, lda, B, ldb, bias, C, ldc, K, alpha, 0, 0, 0, 0);
    else
      gemm64<2, 0, 0><<<g, 256, 0, stream>>>(A, lda, B, ldb, bias, C, ldc, K, alpha, 0, 0, 0, 0);
  };
  // block-diagonal qk gemm: z = head; A[z]: +64 cols, B[z](BT): +64 cols, C[z]: +128 cols
  auto gqk = [&](const float* A, float* C, int M) {
    dim3 g(2, M / 64, 8);
    gemm64<0, 1, 0><<<g, 256, 0, stream>>>(A, 512, T1, 512, nullptr, C, 1024,
                                           64, 1.f, 64, 64, 128, 0);
  };

  tact_kernel<<<1024, 256, 0, stream>>>(t_in, te_w1, te_b1, S2);

  // act1 = silu(x_t @ fe_w1 + fe_b1)
  gfull(1, x_t, 128, fe_w1, 512, fe_b1, S3, 512, 512, 512, 128, 1.f);
  // xcat = [x_emb | t_emb]
  gpart(S3, 512, fe_w2, 512, 512, 512, 512, 4);
  gred(0, fe_b2, S0, 512, 9, 1024, 262144, 4, 1.f);
  gpart(S2, 512, te_w2, 512, 512, 512, 512, 4);
  gred(0, te_b2, S0 + 512, 512, 9, 1024, 262144, 4, 1.f);

  // per-b feature processor (f-broadcast collapsed)
  gpart(S0, 1024, fp_w1, 512, 512, 512, 1024, 4);
  gred(1, fp_b1, S2, 512, 9, 512, 262144, 4, 1.f);   // h1
  gpart(S2, 512, fp_w2, 512, 512, 512, 512, 4);
  gred(1, fp_b2, S3, 512, 9, 512, 262144, 4, 1.f);   // h2
  gpart(S3, 512, fp_w3, 512, 512, 512, 512, 4);
  gred(0, fp_b3, S2, 512, 9, 512, 262144, 4, 1.f);   // base

  // q/v base parts; fid parts (kf' absorbs 0.1 and 1/8)
  gpart(S2, 512, wq, 512, 512, 512, 512, 4);
  gred(0, bq, qb, 512, 9, 512, 262144, 4, 1.f);      // qb
  gpart(S2, 512, wv, 512, 512, 512, 512, 4);
  gred(0, bv, vbuf, 512, 9, 512, 262144, 4, 1.f);    // vb
  gfull(0, fid, 128, wq, 512, nullptr, T0, 512, 128, 512, 128, 0.1f);    // qf
  gfull(0, fid, 128, wk, 512, nullptr, T1, 512, 128, 512, 128, 0.0125f); // kf'
  gfull(0, fid, 128, wv, 512, nullptr, T2, 512, 128, 512, 128, 0.1f);    // vf

  // M[h,i,j] and u[b,h,j] (block-diagonal gemms, z = head)
  gqk(T0, T3, 128);  // M
  gqk(qb, S1, 512);  // u

  // fused sparse attention + mean-pool -> pool (S3)
  attn_kernel<<<dim3(512, 8), 256, 0, stream>>>(S1, T3, vbuf, T2, S3);

  // global processor
  gpart(S3, 512, wo, 512, 512, 512, 512, 4);
  gred(0, bo, S2, 512, 9, 512, 262144, 4, 1.f);      // g1
  gpart(S2, 512, gp_w1, 1024, 512, 1024, 512, 2);
  gred(1, gp_b1, S1, 1024, 10, 1024, 524288, 2, 1.f); // g2
  gpart(S1, 1024, gp_w2, 512, 512, 512, 1024, 4);
  gred(0, gp_b2, S3, 512, 9, 512, 262144, 4, 1.f);   // g3
  ln_kernel<<<512, 256, 0, stream>>>(S3, ln_g, ln_b, S2);  // gn

  // denoise net -> tanh of first 128 cols (f32 out)
  gpart(S2, 512, dn_w1, 1024, 512, 1024, 512, 2);
  gred(1, dn_b1, S1, 1024, 10, 1024, 524288, 2, 1.f); // r1
  gpart(S1, 1024, dn_w2, 1024, 512, 1024, 1024, 2);
  gred(1, dn_b2, S0, 1024, 10, 1024, 524288, 2, 1.f); // r2
  gpart(S0, 1024, dn_w3, 256, 512, 128, 1024, 8);
  gred(2, dn_b3, (float*)d_out, 128, 7, 128, 65536, 8, 1.f); // tanh
}